// Round 1
// baseline (131.429 us; speedup 1.0000x reference)
//
#include <hip/hip_runtime.h>

#define NG 8
#define NT 4096
#define DIN 1024
#define DOUT 4096
#define BM 128
#define BN 128
#define BK 64

typedef __attribute__((ext_vector_type(4))) float f32x4;
typedef __attribute__((ext_vector_type(8))) short bf16x8;

__device__ __forceinline__ unsigned short f2bf(float f) {
    union { float f; unsigned u; } v; v.f = f;
    unsigned u = v.u;
    u += 0x7fffu + ((u >> 16) & 1u);   // RNE round to bf16
    return (unsigned short)(u >> 16);
}

// swizzled byte offset within a [rows][BK] bf16 LDS tile (row pitch 128B)
__device__ __forceinline__ int swz(int row, int colb) {
    return row * (BK * 2) + (colb ^ ((row & 7) << 4));
}

__global__ __launch_bounds__(256, 2)
void grouped_gemm_bf16(const float* __restrict__ x,
                       const int* __restrict__ offs,
                       const float* __restrict__ w,
                       float* __restrict__ out) {
    __shared__ char lds[2 * BM * BK * 2];   // A tile then B tile, bf16
    char* lA = lds;
    char* lB = lds + BM * BK * 2;

    // ---- map blockIdx.y -> (group, row0) with group-aligned tiles ----
    const int rt = blockIdx.y;
    const int n0 = blockIdx.x * BN;
    int row0 = 0, endg = 0, gsel = -1;
    {
        int acc = 0, prev = 0;
        for (int g = 0; g < NG; ++g) {
            int e = offs[g];
            int cnt = (e - prev + BM - 1) / BM;
            if (rt < acc + cnt) { gsel = g; row0 = prev + (rt - acc) * BM; endg = e; break; }
            acc += cnt; prev = e;
        }
    }
    if (gsel < 0) return;

    const float* wg = w + (size_t)gsel * DOUT * DIN;

    const int tid  = threadIdx.x;
    const int lane = tid & 63;
    const int wid  = tid >> 6;
    const int wr   = wid >> 1, wc = wid & 1;   // 2x2 wave grid
    const int lrow = lane & 15, kgrp = lane >> 4;
    const int sr   = tid >> 4;                 // staging row base (0..15)
    const int sc4  = tid & 15;                 // staging float4 col (0..15)

    f32x4 acc[4][4];
    #pragma unroll
    for (int m = 0; m < 4; ++m)
        #pragma unroll
        for (int n = 0; n < 4; ++n)
            acc[m][n] = (f32x4){0.f, 0.f, 0.f, 0.f};

    for (int kt = 0; kt < DIN / BK; ++kt) {
        const int k0 = kt * BK;

        // ---- stage A (x rows, zero-fill beyond group end) ----
        #pragma unroll
        for (int i = 0; i < 8; ++i) {
            int r = sr + i * 16;
            int grow = row0 + r;
            f32x4 v = (f32x4){0.f, 0.f, 0.f, 0.f};
            if (grow < endg)
                v = *(const f32x4*)(x + (size_t)grow * DIN + k0 + sc4 * 4);
            unsigned long long p =
                 (unsigned long long)f2bf(v[0])
               | ((unsigned long long)f2bf(v[1]) << 16)
               | ((unsigned long long)f2bf(v[2]) << 32)
               | ((unsigned long long)f2bf(v[3]) << 48);
            *(unsigned long long*)(lA + swz(r, sc4 * 8)) = p;
        }
        // ---- stage B (weight rows n0..n0+127, always in-bounds) ----
        #pragma unroll
        for (int i = 0; i < 8; ++i) {
            int r = sr + i * 16;
            f32x4 v = *(const f32x4*)(wg + (size_t)(n0 + r) * DIN + k0 + sc4 * 4);
            unsigned long long p =
                 (unsigned long long)f2bf(v[0])
               | ((unsigned long long)f2bf(v[1]) << 16)
               | ((unsigned long long)f2bf(v[2]) << 32)
               | ((unsigned long long)f2bf(v[3]) << 48);
            *(unsigned long long*)(lB + swz(r, sc4 * 8)) = p;
        }
        __syncthreads();

        // ---- MFMA: two K=32 sub-steps ----
        #pragma unroll
        for (int kk = 0; kk < 2; ++kk) {
            const int kb = kk * 64 + kgrp * 16;   // byte col within tile row
            bf16x8 af[4], bf[4];
            #pragma unroll
            for (int m = 0; m < 4; ++m) {
                int r = wr * 64 + m * 16 + lrow;
                af[m] = *(const bf16x8*)(lA + swz(r, kb));
            }
            #pragma unroll
            for (int n = 0; n < 4; ++n) {
                int r = wc * 64 + n * 16 + lrow;
                bf[n] = *(const bf16x8*)(lB + swz(r, kb));
            }
            #pragma unroll
            for (int m = 0; m < 4; ++m)
                #pragma unroll
                for (int n = 0; n < 4; ++n)
                    acc[m][n] = __builtin_amdgcn_mfma_f32_16x16x32_bf16(
                        af[m], bf[n], acc[m][n], 0, 0, 0);
        }
        __syncthreads();
    }

    // ---- epilogue: C/D layout col=lane&15, row=(lane>>4)*4+j ----
    #pragma unroll
    for (int m = 0; m < 4; ++m) {
        #pragma unroll
        for (int j = 0; j < 4; ++j) {
            int row = row0 + wr * 64 + m * 16 + kgrp * 4 + j;
            if (row < endg) {
                #pragma unroll
                for (int n = 0; n < 4; ++n) {
                    int col = n0 + wc * 64 + n * 16 + lrow;
                    out[(size_t)row * DOUT + col] = acc[m][n][j];
                }
            }
        }
    }
}

extern "C" void kernel_launch(void* const* d_in, const int* in_sizes, int n_in,
                              void* d_out, int out_size, void* d_ws, size_t ws_size,
                              hipStream_t stream) {
    const float* x    = (const float*)d_in[0];
    const int*   offs = (const int*)d_in[1];
    const float* w    = (const float*)d_in[2];
    float* out = (float*)d_out;

    // 32 n-tiles; row-tile slots = T/BM + G (worst case sum of per-group ceils)
    dim3 grid(DOUT / BN, NT / BM + NG, 1);
    grouped_gemm_bf16<<<grid, 256, 0, stream>>>(x, offs, w, out);
}

// Round 3
// 104.896 us; speedup vs baseline: 1.2530x; 1.2530x over previous
//
#include <hip/hip_runtime.h>
#include <hip/hip_bf16.h>

#define NG 8
#define NT 4096
#define DIN 1024
#define DOUT 4096
#define BM 128
#define BN 128
#define BK 64
#define KTILES (DIN / BK)   // 16

typedef __attribute__((ext_vector_type(4))) float f32x4;
typedef __attribute__((ext_vector_type(8))) short bf16x8;

// swizzled byte offset within a [rows][BK] bf16 LDS tile (row pitch 128B)
__device__ __forceinline__ int swz(int row, int colb) {
    return row * (BK * 2) + (colb ^ ((row & 7) << 4));
}

// 4×f32 -> packed 4×bf16 (compiler emits v_cvt_pk_bf16_f32 pairs)
__device__ __forceinline__ unsigned long long pack4bf(f32x4 v) {
    union { __hip_bfloat16 h; unsigned short u; } c0, c1, c2, c3;
    c0.h = __float2bfloat16(v[0]);
    c1.h = __float2bfloat16(v[1]);
    c2.h = __float2bfloat16(v[2]);
    c3.h = __float2bfloat16(v[3]);
    return (unsigned long long)c0.u | ((unsigned long long)c1.u << 16) |
           ((unsigned long long)c2.u << 32) | ((unsigned long long)c3.u << 48);
}

__global__ __launch_bounds__(256, 2)
void grouped_gemm_bf16(const float* __restrict__ x,
                       const int* __restrict__ offs,
                       const float* __restrict__ w,
                       float* __restrict__ out) {
    // single buffer: A tile 16KB + B tile 16KB (R1 layout)
    __shared__ char lds[2 * BM * BK * 2];
    char* lA = lds;
    char* lB = lds + BM * BK * 2;

    // ---- map blockIdx.y -> (group, row0), group-aligned row tiles ----
    const int rt = blockIdx.y;
    const int n0 = blockIdx.x * BN;
    int row0 = 0, endg = 0, gsel = -1;
    {
        int acc = 0, prev = 0;
        for (int g = 0; g < NG; ++g) {
            int e = offs[g];
            int cnt = (e - prev + BM - 1) / BM;
            if (rt < acc + cnt) { gsel = g; row0 = prev + (rt - acc) * BM; endg = e; break; }
            acc += cnt; prev = e;
        }
    }
    if (gsel < 0) return;
    const float* wg = w + (size_t)gsel * DOUT * DIN;

    const int tid  = threadIdx.x;
    const int lane = tid & 63;
    const int wid  = tid >> 6;
    const int wr   = wid >> 1, wc = wid & 1;     // 2x2 wave grid
    const int lrow = lane & 15, kgrp = lane >> 4;
    const int sr   = tid >> 4;                   // staging row base (0..15)
    const int sc4  = tid & 15;                   // staging float4 col

    // per-slice staging source offsets (32-bit element offsets)
    int aoff[8], boff[8];
    bool am[8];
    #pragma unroll
    for (int i = 0; i < 8; ++i) {
        int grow = row0 + sr + i * 16;
        am[i] = grow < endg;
        int srow = am[i] ? grow : row0;          // clamp OOB rows to a valid row
        aoff[i] = srow * DIN + sc4 * 4;
        boff[i] = (n0 + sr + i * 16) * DIN + sc4 * 4;
    }

    f32x4 acc[4][4];
    #pragma unroll
    for (int m = 0; m < 4; ++m)
        #pragma unroll
        for (int n = 0; n < 4; ++n)
            acc[m][n] = (f32x4){0.f, 0.f, 0.f, 0.f};

    f32x4 pA[8], pB[8];

    // ---- prologue: load + stage tile 0 ----
    #pragma unroll
    for (int i = 0; i < 8; ++i) pA[i] = *(const f32x4*)(x + aoff[i]);
    #pragma unroll
    for (int i = 0; i < 8; ++i) pB[i] = *(const f32x4*)(wg + boff[i]);
    #pragma unroll
    for (int i = 0; i < 8; ++i) {
        f32x4 v = am[i] ? pA[i] : (f32x4){0.f, 0.f, 0.f, 0.f};
        *(unsigned long long*)(lA + swz(sr + i * 16, sc4 * 8)) = pack4bf(v);
    }
    #pragma unroll
    for (int i = 0; i < 8; ++i)
        *(unsigned long long*)(lB + swz(sr + i * 16, sc4 * 8)) = pack4bf(pB[i]);
    __syncthreads();

    for (int kt = 0; kt < KTILES; ++kt) {
        // ---- issue next tile's global loads BEFORE compute (latency hides) ----
        if (kt + 1 < KTILES) {
            const int k0 = (kt + 1) * BK;
            #pragma unroll
            for (int i = 0; i < 8; ++i) pA[i] = *(const f32x4*)(x + aoff[i] + k0);
            #pragma unroll
            for (int i = 0; i < 8; ++i) pB[i] = *(const f32x4*)(wg + boff[i] + k0);
        }

        // ---- compute current tile from LDS ----
        #pragma unroll
        for (int kk = 0; kk < 2; ++kk) {
            const int kb = kk * 64 + kgrp * 16;
            bf16x8 af[4], bb[4];
            #pragma unroll
            for (int m = 0; m < 4; ++m)
                af[m] = *(const bf16x8*)(lA + swz(wr * 64 + m * 16 + lrow, kb));
            #pragma unroll
            for (int n = 0; n < 4; ++n)
                bb[n] = *(const bf16x8*)(lB + swz(wc * 64 + n * 16 + lrow, kb));
            #pragma unroll
            for (int m = 0; m < 4; ++m)
                #pragma unroll
                for (int n = 0; n < 4; ++n)
                    acc[m][n] = __builtin_amdgcn_mfma_f32_16x16x32_bf16(
                        af[m], bb[n], acc[m][n], 0, 0, 0);
        }
        __syncthreads();   // all waves done reading this tile

        // ---- overwrite LDS with next tile (write-late), then make visible ----
        if (kt + 1 < KTILES) {
            #pragma unroll
            for (int i = 0; i < 8; ++i) {
                f32x4 v = am[i] ? pA[i] : (f32x4){0.f, 0.f, 0.f, 0.f};
                *(unsigned long long*)(lA + swz(sr + i * 16, sc4 * 8)) = pack4bf(v);
            }
            #pragma unroll
            for (int i = 0; i < 8; ++i)
                *(unsigned long long*)(lB + swz(sr + i * 16, sc4 * 8)) = pack4bf(pB[i]);
            __syncthreads();
        }
    }

    // ---- epilogue: C/D layout col=lane&15, row=(lane>>4)*4+j ----
    #pragma unroll
    for (int m = 0; m < 4; ++m) {
        #pragma unroll
        for (int j = 0; j < 4; ++j) {
            int row = row0 + wr * 64 + m * 16 + kgrp * 4 + j;
            if (row < endg) {
                #pragma unroll
                for (int n = 0; n < 4; ++n) {
                    int col = n0 + wc * 64 + n * 16 + lrow;
                    out[(size_t)row * DOUT + col] = acc[m][n][j];
                }
            }
        }
    }
}

extern "C" void kernel_launch(void* const* d_in, const int* in_sizes, int n_in,
                              void* d_out, int out_size, void* d_ws, size_t ws_size,
                              hipStream_t stream) {
    const float* x    = (const float*)d_in[0];
    const int*   offs = (const int*)d_in[1];
    const float* w    = (const float*)d_in[2];
    float* out = (float*)d_out;

    dim3 grid(DOUT / BN, NT / BM + NG, 1);
    grouped_gemm_bf16<<<grid, 256, 0, stream>>>(x, offs, w, out);
}

// Round 4
// 85.878 us; speedup vs baseline: 1.5304x; 1.2215x over previous
//
#include <hip/hip_runtime.h>
#include <hip/hip_bf16.h>

#define NG 8
#define NT 4096
#define DIN 1024
#define DOUT 4096
#define BM 128
#define BN 128
#define BK 32
#define KTILES (DIN / BK)   // 32

typedef __attribute__((ext_vector_type(4))) float f32x4;
typedef __attribute__((ext_vector_type(8))) short bf16x8;

// async global->LDS, 16B per lane; LDS dest is wave-uniform base + lane*16
__device__ __forceinline__ void gld16(const float* g, float* l) {
    __builtin_amdgcn_global_load_lds(
        (const __attribute__((address_space(1))) void*)(g),
        (__attribute__((address_space(3))) void*)(l), 16, 0, 0);
}

// build bf16x8 from 8 f32 (compiler pairs into v_cvt_pk_bf16_f32)
__device__ __forceinline__ bf16x8 cvt8(f32x4 lo, f32x4 hi) {
    union { bf16x8 v; unsigned short s[8]; } u;
    union { __hip_bfloat16 h; unsigned short b; } t;
    t.h = __float2bfloat16(lo[0]); u.s[0] = t.b;
    t.h = __float2bfloat16(lo[1]); u.s[1] = t.b;
    t.h = __float2bfloat16(lo[2]); u.s[2] = t.b;
    t.h = __float2bfloat16(lo[3]); u.s[3] = t.b;
    t.h = __float2bfloat16(hi[0]); u.s[4] = t.b;
    t.h = __float2bfloat16(hi[1]); u.s[5] = t.b;
    t.h = __float2bfloat16(hi[2]); u.s[6] = t.b;
    t.h = __float2bfloat16(hi[3]); u.s[7] = t.b;
    return u.v;
}

__global__ __launch_bounds__(256, 2)
void grouped_gemm_bf16(const float* __restrict__ x,
                       const int* __restrict__ offs,
                       const float* __restrict__ w,
                       float* __restrict__ out) {
    // double-buffered f32 tiles: 2 x (A 16KB + B 16KB) = 64KB
    __shared__ float lds[2 * 2 * BM * BK];

    // ---- map blockIdx.y -> (group, row0), group-aligned row tiles ----
    const int rt = blockIdx.y;
    const int n0 = blockIdx.x * BN;
    int row0 = 0, endg = 0, gsel = -1;
    {
        int acc = 0, prev = 0;
        for (int g = 0; g < NG; ++g) {
            int e = offs[g];
            int cnt = (e - prev + BM - 1) / BM;
            if (rt < acc + cnt) { gsel = g; row0 = prev + (rt - acc) * BM; endg = e; break; }
            acc += cnt; prev = e;
        }
    }
    if (gsel < 0) return;
    const float* wg = w + (size_t)gsel * DOUT * DIN;

    const int tid  = threadIdx.x;
    const int lane = tid & 63;
    const int wid  = tid >> 6;
    const int wr   = wid >> 1, wc = wid & 1;     // 2x2 wave grid
    const int lrow = lane & 15, kgrp = lane >> 4;

    // ---- staging geometry ----
    // issue i (0..3): wave wid covers stripe = i*4+wid (8 rows x 128B = 1KB).
    // lane -> row r = stripe*8 + (lane>>3), dest 16B slot c = lane&7.
    // source chunk = c ^ (r&7)  (inverse swizzle; read side applies same XOR)
    int aoff[4], boff[4], sbase[4];
    #pragma unroll
    for (int i = 0; i < 4; ++i) {
        int stripe = i * 4 + wid;
        int r = stripe * 8 + (lane >> 3);
        int cs = (lane & 7) ^ (r & 7);
        int ar = row0 + r; if (ar >= endg) ar = endg - 1;   // clamp; outputs masked
        aoff[i]  = ar * DIN + cs * 4;
        boff[i]  = (n0 + r) * DIN + cs * 4;
        sbase[i] = stripe * 256;                 // floats (wave-uniform)
    }

    f32x4 acc[4][4];
    #pragma unroll
    for (int m = 0; m < 4; ++m)
        #pragma unroll
        for (int n = 0; n < 4; ++n)
            acc[m][n] = (f32x4){0.f, 0.f, 0.f, 0.f};

    // ---- prologue: stage tile 0 into buf 0 ----
    {
        float* bA = lds;
        float* bB = lds + BM * BK;
        #pragma unroll
        for (int i = 0; i < 4; ++i) {
            gld16(x  + aoff[i], bA + sbase[i]);
            gld16(wg + boff[i], bB + sbase[i]);
        }
    }
    __syncthreads();   // drains vmcnt -> tile 0 ready

    for (int kt = 0; kt < KTILES; ++kt) {
        const int cur = kt & 1;

        // ---- STAGE next tile (fire-and-forget HW DMA into other buffer) ----
        if (kt + 1 < KTILES) {
            const int k0 = (kt + 1) * BK;
            float* bA = lds + (cur ^ 1) * (2 * BM * BK);
            float* bB = bA + BM * BK;
            #pragma unroll
            for (int i = 0; i < 4; ++i) {
                gld16(x  + aoff[i] + k0, bA + sbase[i]);
                gld16(wg + boff[i] + k0, bB + sbase[i]);
            }
        }

        // ---- compute current tile: ds_read f32 pairs -> cvt -> 16 MFMA ----
        {
            const float* bA = lds + cur * (2 * BM * BK);
            const float* bB = bA + BM * BK;
            bf16x8 af[4], bb[4];
            #pragma unroll
            for (int m = 0; m < 4; ++m) {
                int tr = wr * 64 + m * 16 + lrow;
                const float* p = bA + tr * BK;
                int c0 = (kgrp * 2)     ^ (tr & 7);
                int c1 = (kgrp * 2 + 1) ^ (tr & 7);
                af[m] = cvt8(*(const f32x4*)(p + c0 * 4), *(const f32x4*)(p + c1 * 4));
            }
            #pragma unroll
            for (int n = 0; n < 4; ++n) {
                int tr = wc * 64 + n * 16 + lrow;
                const float* p = bB + tr * BK;
                int c0 = (kgrp * 2)     ^ (tr & 7);
                int c1 = (kgrp * 2 + 1) ^ (tr & 7);
                bb[n] = cvt8(*(const f32x4*)(p + c0 * 4), *(const f32x4*)(p + c1 * 4));
            }
            #pragma unroll
            for (int m = 0; m < 4; ++m)
                #pragma unroll
                for (int n = 0; n < 4; ++n)
                    acc[m][n] = __builtin_amdgcn_mfma_f32_16x16x32_bf16(
                        af[m], bb[n], acc[m][n], 0, 0, 0);
        }

        // one barrier per step: (a) next-tile DMA drained (vmcnt0 in barrier),
        // (b) all waves done reading buf[cur] before it's overwritten next iter
        __syncthreads();
    }

    // ---- epilogue: C/D layout col=lane&15, row=(lane>>4)*4+j ----
    #pragma unroll
    for (int m = 0; m < 4; ++m) {
        #pragma unroll
        for (int j = 0; j < 4; ++j) {
            int row = row0 + wr * 64 + m * 16 + (lane >> 4) * 4 + j;
            if (row < endg) {
                #pragma unroll
                for (int n = 0; n < 4; ++n) {
                    int col = n0 + wc * 64 + n * 16 + lrow;
                    out[(size_t)row * DOUT + col] = acc[m][n][j];
                }
            }
        }
    }
}

extern "C" void kernel_launch(void* const* d_in, const int* in_sizes, int n_in,
                              void* d_out, int out_size, void* d_ws, size_t ws_size,
                              hipStream_t stream) {
    const float* x    = (const float*)d_in[0];
    const int*   offs = (const int*)d_in[1];
    const float* w    = (const float*)d_in[2];
    float* out = (float*)d_out;

    dim3 grid(DOUT / BN, NT / BM + NG, 1);
    grouped_gemm_bf16<<<grid, 256, 0, stream>>>(x, offs, w, out);
}